// Round 1
// baseline (378.996 us; speedup 1.0000x reference)
//
#include <hip/hip_runtime.h>
#include <hip/hip_bf16.h>

typedef __bf16 bf16_t;
typedef __bf16 bf16x8 __attribute__((ext_vector_type(8)));
typedef float f32x4 __attribute__((ext_vector_type(4)));

#define B_ 8
#define LQ_ 2048
#define LK_ 2048
#define DM_ 1024

__device__ __forceinline__ void gload16(const void* g, void* l) {
  __builtin_amdgcn_global_load_lds(
      (const __attribute__((address_space(1))) void*)g,
      (__attribute__((address_space(3))) void*)l, 16, 0, 0);
}

// ---------------- f32 -> bf16 convert (vectorized) ----------------
__global__ __launch_bounds__(256) void cvt_bf16_kernel(
    const float* __restrict__ in, bf16_t* __restrict__ out, int n8) {
  int stride = gridDim.x * blockDim.x;
  for (int i = blockIdx.x * blockDim.x + threadIdx.x; i < n8; i += stride) {
    const float4* p = reinterpret_cast<const float4*>(in) + (size_t)i * 2;
    float4 a = p[0], b = p[1];
    bf16x8 o;
    o[0] = (bf16_t)a.x; o[1] = (bf16_t)a.y; o[2] = (bf16_t)a.z; o[3] = (bf16_t)a.w;
    o[4] = (bf16_t)b.x; o[5] = (bf16_t)b.y; o[6] = (bf16_t)b.z; o[7] = (bf16_t)b.w;
    *reinterpret_cast<bf16x8*>(out + (size_t)i * 8) = o;
  }
}

// ---------------- V [B][LK][DM] f32 -> Vt [B][DM][LK] bf16 ----------------
__global__ __launch_bounds__(256) void transpose_v(
    const float* __restrict__ V, bf16_t* __restrict__ Vt) {
  __shared__ bf16_t tile[64][65];
  int b = blockIdx.z;
  int k0 = blockIdx.x * 64;
  int d0 = blockIdx.y * 64;
  int r = threadIdx.x >> 6;  // 0..3
  int c = threadIdx.x & 63;
  const float* src = V + ((size_t)b * LK_ + k0) * DM_ + d0;
#pragma unroll
  for (int i = 0; i < 64; i += 4)
    tile[r + i][c] = (bf16_t)src[(size_t)(r + i) * DM_ + c];
  __syncthreads();
  bf16_t* dst = Vt + ((size_t)b * DM_ + d0) * LK_ + k0;
#pragma unroll
  for (int i = 0; i < 64; i += 4)
    dst[(size_t)(r + i) * LK_ + c] = tile[c][r + i];
}

// ---------------- m97-style 128x128 GEMM, C = A * B^T ----------------
// A: [M][K] bf16 row-major, B: [N][K] bf16 row-major.
// MODE 0: C bf16, C += bias[col]              (Q projection)
// MODE 1: C bf16, C = C*(1/32) + mask[b][col] (logits)
// MODE 2: C f32                                (attention output)
template <int MODE>
__global__ __launch_bounds__(256) void gemm_bt(
    const bf16_t* __restrict__ A, const bf16_t* __restrict__ Bm,
    void* __restrict__ Cv, const float* __restrict__ extra,
    int M, int N, int K, long sA, long sB, long sC, long sE) {
  __shared__ bf16_t Al[128 * 32];
  __shared__ bf16_t Bl[128 * 32];
  const int bz = blockIdx.z;
  const bf16_t* Ab = A + (long)bz * sA;
  const bf16_t* Bb = Bm + (long)bz * sB;
  const int lane = threadIdx.x & 63;
  const int wave = threadIdx.x >> 6;
  const int row0 = blockIdx.y * 128;
  const int col0 = blockIdx.x * 128;
  const int wr = wave >> 1, wc = wave & 1;

  f32x4 acc[4][4] = {};

  const int ch0 = wave * 64 + lane;
  const int k8 = (lane >> 4) * 8;
  const int fr = lane & 15;

  for (int kb = 0; kb < K; kb += 32) {
#pragma unroll
    for (int i = 0; i < 512; i += 256) {
      int ch = ch0 + i;
      int r = ch >> 2;
      int c = (ch & 3) * 8;
      gload16(Ab + (long)(row0 + r) * K + kb + c, Al + (size_t)(wave * 64 + i) * 8);
      gload16(Bb + (long)(col0 + r) * K + kb + c, Bl + (size_t)(wave * 64 + i) * 8);
    }
    __syncthreads();
    bf16x8 af[4], bfr[4];
#pragma unroll
    for (int m = 0; m < 4; ++m)
      af[m] = *reinterpret_cast<const bf16x8*>(Al + (wr * 64 + m * 16 + fr) * 32 + k8);
#pragma unroll
    for (int n = 0; n < 4; ++n)
      bfr[n] = *reinterpret_cast<const bf16x8*>(Bl + (wc * 64 + n * 16 + fr) * 32 + k8);
#pragma unroll
    for (int m = 0; m < 4; ++m)
#pragma unroll
      for (int n = 0; n < 4; ++n)
        acc[m][n] = __builtin_amdgcn_mfma_f32_16x16x32_bf16(af[m], bfr[n], acc[m][n], 0, 0, 0);
    __syncthreads();
  }

  const int cn = lane & 15;
  const int rr = (lane >> 4) * 4;
#pragma unroll
  for (int m = 0; m < 4; ++m) {
#pragma unroll
    for (int n = 0; n < 4; ++n) {
      int row = row0 + wr * 64 + m * 16 + rr;
      int col = col0 + wc * 64 + n * 16 + cn;
      if (MODE == 0) {
        bf16_t* C = (bf16_t*)Cv;
        float bias = extra[col];
#pragma unroll
        for (int j = 0; j < 4; ++j)
          C[(long)(row + j) * N + col] = (bf16_t)(acc[m][n][j] + bias);
      } else if (MODE == 1) {
        bf16_t* C = (bf16_t*)Cv + (long)bz * sC;
        float mk = extra[(long)bz * sE + col];
#pragma unroll
        for (int j = 0; j < 4; ++j)
          C[(long)(row + j) * N + col] = (bf16_t)(acc[m][n][j] * 0.03125f + mk);
      } else {
        float* C = (float*)Cv + (long)bz * sC;
#pragma unroll
        for (int j = 0; j < 4; ++j)
          C[(long)(row + j) * N + col] = acc[m][n][j];
      }
    }
  }
}

// ---------------- row softmax, in-place on bf16 logits ----------------
__global__ __launch_bounds__(256) void softmax_rows(bf16_t* __restrict__ logits) {
  long row = blockIdx.x;
  bf16_t* p = logits + row * LK_;
  int t = threadIdx.x;
  int lane = t & 63, wave = t >> 6;
  bf16x8 v = *reinterpret_cast<const bf16x8*>(p + t * 8);
  float f[8];
  float mx = -3e38f;
#pragma unroll
  for (int j = 0; j < 8; ++j) {
    f[j] = (float)v[j];
    mx = fmaxf(mx, f[j]);
  }
#pragma unroll
  for (int off = 32; off > 0; off >>= 1) mx = fmaxf(mx, __shfl_xor(mx, off, 64));
  __shared__ float red[8];
  if (lane == 0) red[wave] = mx;
  __syncthreads();
  mx = fmaxf(fmaxf(red[0], red[1]), fmaxf(red[2], red[3]));
  float s = 0.f;
#pragma unroll
  for (int j = 0; j < 8; ++j) {
    f[j] = __expf(f[j] - mx);
    s += f[j];
  }
#pragma unroll
  for (int off = 32; off > 0; off >>= 1) s += __shfl_xor(s, off, 64);
  if (lane == 0) red[4 + wave] = s;
  __syncthreads();
  s = red[4] + red[5] + red[6] + red[7];
  float inv = 1.f / s;
#pragma unroll
  for (int j = 0; j < 8; ++j) v[j] = (bf16_t)(f[j] * inv);
  *reinterpret_cast<bf16x8*>(p + t * 8) = v;
}

extern "C" void kernel_launch(void* const* d_in, const int* in_sizes, int n_in,
                              void* d_out, int out_size, void* d_ws, size_t ws_size,
                              hipStream_t stream) {
  const float* x    = (const float*)d_in[0];
  const float* mask = (const float*)d_in[1];
  const float* keys = (const float*)d_in[2];
  const float* vals = (const float*)d_in[3];
  const float* Wq   = (const float*)d_in[4];
  const float* bq   = (const float*)d_in[5];
  float* out = (float*)d_out;

  char* ws = (char*)d_ws;
  // layout (bytes):
  //   kbf    [0,               33554432)
  //   vt     [33554432,        67108864)
  //   qbf    [67108864,       100663296)
  //   logits [100663296,      167772160)   (first 33.5MB doubles as xbf)
  //   wqbf   [167772160,      169869312)
  bf16_t* kbf    = (bf16_t*)(ws);
  bf16_t* vt     = (bf16_t*)(ws + 33554432);
  bf16_t* qbf    = (bf16_t*)(ws + 67108864);
  bf16_t* logits = (bf16_t*)(ws + 100663296);
  bf16_t* xbf    = logits;  // reused: x_bf dead before logits are written
  bf16_t* wqbf   = (bf16_t*)(ws + 167772160);

  // 1. converts
  cvt_bf16_kernel<<<2048, 256, 0, stream>>>(x, xbf, (B_ * LQ_ * DM_) / 8);
  cvt_bf16_kernel<<<2048, 256, 0, stream>>>(keys, kbf, (B_ * LK_ * DM_) / 8);
  cvt_bf16_kernel<<<256, 256, 0, stream>>>(Wq, wqbf, (DM_ * DM_) / 8);
  transpose_v<<<dim3(LK_ / 64, DM_ / 64, B_), 256, 0, stream>>>(vals, vt);

  // 2. Q = x @ Wq^T + bq   (M=16384, N=1024, K=1024)
  gemm_bt<0><<<dim3(DM_ / 128, (B_ * LQ_) / 128, 1), 256, 0, stream>>>(
      xbf, wqbf, qbf, bq, B_ * LQ_, DM_, DM_, 0, 0, 0, 0);

  // 3. logits = Q @ K^T / 32 + mask   (per batch: M=2048, N=2048, K=1024)
  gemm_bt<1><<<dim3(LK_ / 128, LQ_ / 128, B_), 256, 0, stream>>>(
      qbf, kbf, logits, mask, LQ_, LK_, DM_,
      (long)LQ_ * DM_, (long)LK_ * DM_, (long)LQ_ * LK_, LK_);

  // 4. softmax rows, in place
  softmax_rows<<<B_ * LQ_, 256, 0, stream>>>(logits);

  // 5. out = P @ Vt^T   (per batch: M=2048, N=1024, K=2048)
  gemm_bt<2><<<dim3(DM_ / 128, LQ_ / 128, B_), 256, 0, stream>>>(
      logits, vt, out, nullptr, LQ_, DM_, LK_,
      (long)LQ_ * LK_, (long)DM_ * LK_, (long)LQ_ * DM_, 0);
}

// Round 2
// 268.215 us; speedup vs baseline: 1.4130x; 1.4130x over previous
//
#include <hip/hip_runtime.h>
#include <hip/hip_bf16.h>

typedef __bf16 bf16_t;
typedef __bf16 bf16x8 __attribute__((ext_vector_type(8)));
typedef float f32x4 __attribute__((ext_vector_type(4)));

#define B_ 8
#define LQ_ 2048
#define LK_ 2048
#define DM_ 1024

__device__ __forceinline__ void gload16(const void* g, void* l) {
  __builtin_amdgcn_global_load_lds(
      (const __attribute__((address_space(1))) void*)g,
      (__attribute__((address_space(3))) void*)l, 16, 0, 0);
}

// ---------------- f32 -> bf16 convert (vectorized) ----------------
__global__ __launch_bounds__(256) void cvt_bf16_kernel(
    const float* __restrict__ in, bf16_t* __restrict__ out, int n8) {
  int stride = gridDim.x * blockDim.x;
  for (int i = blockIdx.x * blockDim.x + threadIdx.x; i < n8; i += stride) {
    const float4* p = reinterpret_cast<const float4*>(in) + (size_t)i * 2;
    float4 a = p[0], b = p[1];
    bf16x8 o;
    o[0] = (bf16_t)a.x; o[1] = (bf16_t)a.y; o[2] = (bf16_t)a.z; o[3] = (bf16_t)a.w;
    o[4] = (bf16_t)b.x; o[5] = (bf16_t)b.y; o[6] = (bf16_t)b.z; o[7] = (bf16_t)b.w;
    *reinterpret_cast<bf16x8*>(out + (size_t)i * 8) = o;
  }
}

// ---------------- V [B][LK][DM] f32 -> Vt [B][DM][LK] bf16 ----------------
__global__ __launch_bounds__(256) void transpose_v(
    const float* __restrict__ V, bf16_t* __restrict__ Vt) {
  __shared__ bf16_t tile[64][65];
  int b = blockIdx.z;
  int k0 = blockIdx.x * 64;
  int d0 = blockIdx.y * 64;
  int r = threadIdx.x >> 6;
  int c = threadIdx.x & 63;
  const float* src = V + ((size_t)b * LK_ + k0) * DM_ + d0;
#pragma unroll
  for (int i = 0; i < 64; i += 4)
    tile[r + i][c] = (bf16_t)src[(size_t)(r + i) * DM_ + c];
  __syncthreads();
  bf16_t* dst = Vt + ((size_t)b * DM_ + d0) * LK_ + k0;
#pragma unroll
  for (int i = 0; i < 64; i += 4)
    dst[(size_t)(r + i) * LK_ + c] = tile[c][r + i];
}

// ---------------- 256x256 deep-pipelined GEMM, C = A * B^T ----------------
// A: [M][K] bf16 row-major, B: [N][K] bf16 row-major.
// 8 waves (2x4), wave tile 128x64, BK=32, 4 LDS buffers, 1 barrier/K-tile.
// K-slot swizzle: slot_phys = slot ^ ((row>>1)&3)  (involution, both sides).
// MODE 0: C bf16, C += bias[col]              (Q projection)
// MODE 1: C bf16, C = C*(1/32) + mask[b][col] (logits)
// MODE 2: C f32                                (attention output)
template <int MODE>
__global__ __launch_bounds__(512, 2) void gemm_bt(
    const bf16_t* __restrict__ A, const bf16_t* __restrict__ Bm,
    void* __restrict__ Cv, const float* __restrict__ extra,
    int N, int K, long sA, long sB, long sC, long sE, int gxs, int gys) {
  __shared__ bf16_t lds[4 * 16384];  // 4 bufs x (A 8192 + B 8192) bf16 = 128 KiB

  const int tid = threadIdx.x;
  const int lane = tid & 63;
  const int wave = tid >> 6;

  // XCD-aware bijective block swizzle (gridDim.x % 8 == 0 for all our grids)
  const int nwg = gridDim.x;
  const int lin = blockIdx.x;
  const int cpx = nwg >> 3;
  const int swz = (lin & 7) * cpx + (lin >> 3);
  const int gx = 1 << gxs;
  const int bx = swz & (gx - 1);
  const int rem = swz >> gxs;
  const int by = rem & ((1 << gys) - 1);
  const int bz = rem >> gys;

  const bf16_t* Ab = A + (long)bz * sA + (long)(by * 256) * K;
  const bf16_t* Bb = Bm + (long)bz * sB + (long)(bx * 256) * K;

  // staging geometry: per tile, 2 gload16/matrix: rows tid>>2 (+128), swizzled k-slot
  const int srow = tid >> 2;               // 0..127
  const int sq = (tid >> 3) & 3;           // q(row) = (row>>1)&3
  const int scol = ((tid & 3) ^ sq) * 8;   // pre-swizzled global k-slot (elements)

  // fragment geometry
  const int wr = wave >> 2;                // 0..1
  const int wc = wave & 3;                 // 0..3
  const int fr = lane & 15;
  const int fq = (fr >> 1) & 3;            // q(row) for frag rows
  const int slot = (lane >> 4) ^ fq;       // swizzled read slot
  const int aoff = (wr * 128 + fr) * 32 + slot * 8;         // + m*512
  const int boff = 8192 + (wc * 64 + fr) * 32 + slot * 8;   // + n*512

  auto STAGE = [&](int tt) {
    const int kb = tt * 32;
    bf16_t* buf = lds + (tt & 3) * 16384;
    const bf16_t* ag = Ab + (long)srow * K + kb + scol;
    const bf16_t* bg = Bb + (long)srow * K + kb + scol;
    bf16_t* al = buf + wave * 512;         // wave-uniform LDS base
    bf16_t* bl = buf + 8192 + wave * 512;
    gload16(ag, al);
    gload16(ag + (long)128 * K, al + 4096);
    gload16(bg, bl);
    gload16(bg + (long)128 * K, bl + 4096);
  };

  f32x4 acc[8][4] = {};
  const int NT = K >> 5;  // requires NT >= 4 (true: K is 1024 or 2048)

  STAGE(0); STAGE(1); STAGE(2);                 // 12 loads in flight
  asm volatile("s_waitcnt vmcnt(8)" ::: "memory");  // tile 0 complete
  __builtin_amdgcn_s_barrier();

  for (int t = 0; t < NT; ++t) {
    const bf16_t* buf = lds + (t & 3) * 16384;
    if (t + 3 < NT) STAGE(t + 3);  // -> buf[(t+3)&3], last read in iter t-1: no WAR

    bf16x8 af[8], bfv[4];
#pragma unroll
    for (int m = 0; m < 8; ++m)
      af[m] = *reinterpret_cast<const bf16x8*>(buf + aoff + m * 512);
#pragma unroll
    for (int n = 0; n < 4; ++n)
      bfv[n] = *reinterpret_cast<const bf16x8*>(buf + boff + n * 512);

    __builtin_amdgcn_s_setprio(1);
#pragma unroll
    for (int m = 0; m < 8; ++m)
#pragma unroll
      for (int n = 0; n < 4; ++n)
        acc[m][n] = __builtin_amdgcn_mfma_f32_16x16x32_bf16(af[m], bfv[n], acc[m][n], 0, 0, 0);
    __builtin_amdgcn_s_setprio(0);

    // drain so tile t+1 is complete LDS-wide before the barrier releases waves
    if (t + 3 < NT)      asm volatile("s_waitcnt vmcnt(8)" ::: "memory");
    else if (t + 2 < NT) asm volatile("s_waitcnt vmcnt(4)" ::: "memory");
    else if (t + 1 < NT) asm volatile("s_waitcnt vmcnt(0)" ::: "memory");
    __builtin_amdgcn_s_barrier();
  }

  // epilogue
  const int cn = lane & 15;
  const int rr = (lane >> 4) * 4;
  const int row0 = by * 256 + wr * 128;
  const int col0 = bx * 256 + wc * 64;
#pragma unroll
  for (int m = 0; m < 8; ++m) {
    const int row = row0 + m * 16 + rr;
#pragma unroll
    for (int n = 0; n < 4; ++n) {
      const int col = col0 + n * 16 + cn;
      if (MODE == 0) {
        bf16_t* C = (bf16_t*)Cv;
        float bias = extra[col];
#pragma unroll
        for (int j = 0; j < 4; ++j)
          C[(long)(row + j) * N + col] = (bf16_t)(acc[m][n][j] + bias);
      } else if (MODE == 1) {
        bf16_t* C = (bf16_t*)Cv + (long)bz * sC;
        float mk = extra[(long)bz * sE + col];
#pragma unroll
        for (int j = 0; j < 4; ++j)
          C[(long)(row + j) * N + col] = (bf16_t)(acc[m][n][j] * 0.03125f + mk);
      } else {
        float* C = (float*)Cv + (long)bz * sC;
#pragma unroll
        for (int j = 0; j < 4; ++j)
          C[(long)(row + j) * N + col] = acc[m][n][j];
      }
    }
  }
}

// ---------------- row softmax, in-place on bf16 logits ----------------
__global__ __launch_bounds__(256) void softmax_rows(bf16_t* __restrict__ logits) {
  long row = blockIdx.x;
  bf16_t* p = logits + row * LK_;
  int t = threadIdx.x;
  int lane = t & 63, wave = t >> 6;
  bf16x8 v = *reinterpret_cast<const bf16x8*>(p + t * 8);
  float f[8];
  float mx = -3e38f;
#pragma unroll
  for (int j = 0; j < 8; ++j) {
    f[j] = (float)v[j];
    mx = fmaxf(mx, f[j]);
  }
#pragma unroll
  for (int off = 32; off > 0; off >>= 1) mx = fmaxf(mx, __shfl_xor(mx, off, 64));
  __shared__ float red[8];
  if (lane == 0) red[wave] = mx;
  __syncthreads();
  mx = fmaxf(fmaxf(red[0], red[1]), fmaxf(red[2], red[3]));
  float s = 0.f;
#pragma unroll
  for (int j = 0; j < 8; ++j) {
    f[j] = __expf(f[j] - mx);
    s += f[j];
  }
#pragma unroll
  for (int off = 32; off > 0; off >>= 1) s += __shfl_xor(s, off, 64);
  if (lane == 0) red[4 + wave] = s;
  __syncthreads();
  s = red[4] + red[5] + red[6] + red[7];
  float inv = 1.f / s;
#pragma unroll
  for (int j = 0; j < 8; ++j) v[j] = (bf16_t)(f[j] * inv);
  *reinterpret_cast<bf16x8*>(p + t * 8) = v;
}

extern "C" void kernel_launch(void* const* d_in, const int* in_sizes, int n_in,
                              void* d_out, int out_size, void* d_ws, size_t ws_size,
                              hipStream_t stream) {
  const float* x    = (const float*)d_in[0];
  const float* mask = (const float*)d_in[1];
  const float* keys = (const float*)d_in[2];
  const float* vals = (const float*)d_in[3];
  const float* Wq   = (const float*)d_in[4];
  const float* bq   = (const float*)d_in[5];
  float* out = (float*)d_out;

  char* ws = (char*)d_ws;
  bf16_t* kbf    = (bf16_t*)(ws);
  bf16_t* vt     = (bf16_t*)(ws + 33554432);
  bf16_t* qbf    = (bf16_t*)(ws + 67108864);
  bf16_t* logits = (bf16_t*)(ws + 100663296);
  bf16_t* xbf    = logits;  // reused: x_bf dead before logits are written
  bf16_t* wqbf   = (bf16_t*)(ws + 167772160);

  // 1. converts
  cvt_bf16_kernel<<<2048, 256, 0, stream>>>(x, xbf, (B_ * LQ_ * DM_) / 8);
  cvt_bf16_kernel<<<2048, 256, 0, stream>>>(keys, kbf, (B_ * LK_ * DM_) / 8);
  cvt_bf16_kernel<<<256, 256, 0, stream>>>(Wq, wqbf, (DM_ * DM_) / 8);
  transpose_v<<<dim3(LK_ / 64, DM_ / 64, B_), 256, 0, stream>>>(vals, vt);

  // 2. Q = x @ Wq^T + bq   (M=16384, N=1024, K=1024) grid 4x64 = 256
  gemm_bt<0><<<256, 512, 0, stream>>>(
      xbf, wqbf, qbf, bq, DM_, DM_, 0, 0, 0, 0, 2, 6);

  // 3. logits = Q @ K^T / 32 + mask (per batch M=2048,N=2048,K=1024) grid 8x8x8 = 512
  gemm_bt<1><<<512, 512, 0, stream>>>(
      qbf, kbf, logits, mask, LK_, DM_,
      (long)LQ_ * DM_, (long)LK_ * DM_, (long)LQ_ * LK_, LK_, 3, 3);

  // 4. softmax rows, in place
  softmax_rows<<<B_ * LQ_, 256, 0, stream>>>(logits);

  // 5. out = P @ Vt^T   (per batch M=2048, N=1024, K=2048) grid 4x8x8 = 256
  gemm_bt<2><<<256, 512, 0, stream>>>(
      logits, vt, out, nullptr, DM_, LK_,
      (long)LQ_ * LK_, (long)DM_ * LK_, (long)LQ_ * DM_, 0, 2, 3);
}

// Round 3
// 256.952 us; speedup vs baseline: 1.4750x; 1.0438x over previous
//
#include <hip/hip_runtime.h>
#include <hip/hip_bf16.h>

typedef __bf16 bf16_t;
typedef __bf16 bf16x8 __attribute__((ext_vector_type(8)));
typedef float f32x4 __attribute__((ext_vector_type(4)));

#define B_ 8
#define LQ_ 2048
#define LK_ 2048
#define DM_ 1024

__device__ __forceinline__ void gload16(const void* g, void* l) {
  __builtin_amdgcn_global_load_lds(
      (const __attribute__((address_space(1))) void*)g,
      (__attribute__((address_space(3))) void*)l, 16, 0, 0);
}

// ---------------- f32 -> bf16 convert (vectorized) ----------------
__global__ __launch_bounds__(256) void cvt_bf16_kernel(
    const float* __restrict__ in, bf16_t* __restrict__ out, int n8) {
  int stride = gridDim.x * blockDim.x;
  for (int i = blockIdx.x * blockDim.x + threadIdx.x; i < n8; i += stride) {
    const float4* p = reinterpret_cast<const float4*>(in) + (size_t)i * 2;
    float4 a = p[0], b = p[1];
    bf16x8 o;
    o[0] = (bf16_t)a.x; o[1] = (bf16_t)a.y; o[2] = (bf16_t)a.z; o[3] = (bf16_t)a.w;
    o[4] = (bf16_t)b.x; o[5] = (bf16_t)b.y; o[6] = (bf16_t)b.z; o[7] = (bf16_t)b.w;
    *reinterpret_cast<bf16x8*>(out + (size_t)i * 8) = o;
  }
}

// ---------------- V [B][LK][DM] f32 -> Vt [B][DM][LK] bf16 ----------------
__global__ __launch_bounds__(256) void transpose_v(
    const float* __restrict__ V, bf16_t* __restrict__ Vt) {
  __shared__ bf16_t tile[64][65];
  int b = blockIdx.z;
  int k0 = blockIdx.x * 64;
  int d0 = blockIdx.y * 64;
  int r = threadIdx.x >> 6;
  int c = threadIdx.x & 63;
  const float* src = V + ((size_t)b * LK_ + k0) * DM_ + d0;
#pragma unroll
  for (int i = 0; i < 64; i += 4)
    tile[r + i][c] = (bf16_t)src[(size_t)(r + i) * DM_ + c];
  __syncthreads();
  bf16_t* dst = Vt + ((size_t)b * DM_ + d0) * LK_ + k0;
#pragma unroll
  for (int i = 0; i < 64; i += 4)
    dst[(size_t)(r + i) * LK_ + c] = tile[c][r + i];
}

// ---------------- 256x256 8-phase GEMM, C = A * B^T ----------------
// A: [M][K] bf16 row-major, B: [N][K] bf16 row-major.
// BK=64, 2 K-tiles per iteration, 8 waves (2Mx4N), wave tile 128x64.
// LDS layout (elems): A: [0,32768) = d0[16384] d1[16384]; B: [32768,65536).
// K-slot swizzle (involution): phys_slot = slot ^ ((row>>1)&7), 8 slots of 16B.
// Per phase: {ds_read subtile; stage 1 half-tile; BAR; setprio 16 MFMA; BAR}.
// vmcnt(4) only at phases 4 and 8 (2 half-tiles x 2 loads remain in flight).
// MODE 0: C bf16, C += bias[col]; MODE 1: C bf16, *(1/32)+mask; MODE 2: C f32.
#define BARX __builtin_amdgcn_s_barrier()
#define PRIO1 __builtin_amdgcn_s_setprio(1)
#define PRIO0 __builtin_amdgcn_s_setprio(0)

#define RD_A(QM, DOFF)                                                        \
  _Pragma("unroll") for (int m = 0; m < 4; ++m) {                             \
    aF[m][0] = *(const bf16x8*)(pa0 + (QM)*8192 + (DOFF) + m * 2048);         \
    aF[m][1] = *(const bf16x8*)(pa1 + (QM)*8192 + (DOFF) + m * 2048);         \
  }
#define RD_B2(NB, DOFF)                                                       \
  _Pragma("unroll") for (int n = 0; n < 2; ++n) {                             \
    bF[(NB) + n][0] = *(const bf16x8*)(pb0 + (DOFF) + ((NB) + n) * 2048);     \
    bF[(NB) + n][1] = *(const bf16x8*)(pb1 + (DOFF) + ((NB) + n) * 2048);     \
  }
#define MFMA_QUAD(MB, NB)                                                     \
  _Pragma("unroll") for (int m = 0; m < 4; ++m)                               \
  _Pragma("unroll") for (int n = 0; n < 2; ++n) {                             \
    acc[(MB) + m][(NB) + n] = __builtin_amdgcn_mfma_f32_16x16x32_bf16(        \
        aF[m][0], bF[(NB) + n][0], acc[(MB) + m][(NB) + n], 0, 0, 0);         \
    acc[(MB) + m][(NB) + n] = __builtin_amdgcn_mfma_f32_16x16x32_bf16(        \
        aF[m][1], bF[(NB) + n][1], acc[(MB) + m][(NB) + n], 0, 0, 0);         \
  }

template <int MODE>
__global__ __launch_bounds__(512, 2) void gemm_bt(
    const bf16_t* __restrict__ A, const bf16_t* __restrict__ Bm,
    void* __restrict__ Cv, const float* __restrict__ extra,
    int N, int K, long sA, long sB, long sC, long sE, int gxs, int gys) {
  __shared__ bf16_t lds[65536];  // 128 KiB

  const int tid = threadIdx.x;
  const int lane = tid & 63;
  const int wave = tid >> 6;

  // XCD-aware bijective block swizzle (gridDim.x % 8 == 0 for all our grids)
  const int nwg = gridDim.x;
  const int lin = blockIdx.x;
  const int cpx = nwg >> 3;
  const int swz = (lin & 7) * cpx + (lin >> 3);
  const int gx = 1 << gxs;
  const int bx = swz & (gx - 1);
  const int rem = swz >> gxs;
  const int by = rem & ((1 << gys) - 1);
  const int bz = rem >> gys;

  const bf16_t* Ab = A + (long)bz * sA + (long)(by * 256) * K;
  const bf16_t* Bb = Bm + (long)bz * sB + (long)(bx * 256) * K;

  // staging geometry: chunk c = tid (+512); row-in-half = c>>3, phys slot c&7
  const int r0 = tid >> 3;                              // 0..63
  const int scol = ((tid & 7) ^ ((r0 >> 1) & 7)) * 8;   // pre-swizzled global col

  auto STG = [&](const bf16_t* Mb, int d, int mat, int h, int t) {
    const bf16_t* g = Mb + (long)(h * 128 + r0) * K + t * 64 + scol;
    bf16_t* l = lds + mat * 32768 + d * 16384 + h * 8192 + wave * 512;
    gload16(g, l);
    gload16(g + (long)64 * K, l + 4096);
  };

  // fragment read geometry
  const int wr = wave >> 2;   // 0..1  (A half = wr)
  const int wc = wave & 3;    // 0..3
  const int fr = lane & 15;
  const int g = lane >> 4;
  const int q5 = (fr >> 1) & 7;
  const int sb0 = (g ^ q5) * 16;         // kk=0 slot bytes (phys)
  const int sb1 = ((4 + g) ^ q5) * 16;   // kk=1
  const char* ldsc = (const char*)lds;
  const char* pa0 = ldsc + (wr * 128 + fr) * 128 + sb0;
  const char* pa1 = ldsc + (wr * 128 + fr) * 128 + sb1;
  const char* pb0 = ldsc + 65536 + (wc * 64 + fr) * 128 + sb0;
  const char* pb1 = ldsc + 65536 + (wc * 64 + fr) * 128 + sb1;

  f32x4 acc[8][4] = {};
  bf16x8 aF[4][2], bF[4][2];

  const int NT2 = K >> 7;  // iterations, 2 K-tiles (BK=64) each

  // prologue: t0 full (A h0,h1, B h0,h1) + t1 B h0,h1 = 12 loads
  STG(Ab, 0, 0, 0, 0); STG(Ab, 0, 0, 1, 0);
  STG(Bb, 0, 1, 0, 0); STG(Bb, 0, 1, 1, 0);
  STG(Bb, 1, 1, 0, 1); STG(Bb, 1, 1, 1, 1);
  asm volatile("s_waitcnt vmcnt(4)" ::: "memory");  // t0 complete, t1.B in flight
  BARX;

  for (int j = 0; j < NT2; ++j) {
    const bool nl = (j + 1 < NT2);
    const int t1 = 2 * j + 1, t2 = 2 * j + 2, t3 = 2 * j + 3;
    // ---- P1: quadrant (qm0,qn01) of dbuf0 ----
    RD_A(0, 0); RD_B2(0, 0);
    STG(Ab, 1, 0, 0, t1);
    BARX; PRIO1; MFMA_QUAD(0, 0); PRIO0; BARX;
    // ---- P2: (qm0,qn23) ----
    RD_B2(2, 0);
    STG(Ab, 1, 0, 1, t1);
    BARX; PRIO1; MFMA_QUAD(0, 2); PRIO0; BARX;
    // ---- P3: (qm1,qn23) ----
    RD_A(1, 0);
    if (nl) STG(Bb, 0, 1, 0, t2);
    BARX; PRIO1; MFMA_QUAD(4, 2); PRIO0; BARX;
    // ---- P4: (qm1,qn01); dbuf1 must be complete after this phase ----
    if (nl) STG(Bb, 0, 1, 1, t2);
    BARX; PRIO1; MFMA_QUAD(4, 0); PRIO0;
    if (nl) { asm volatile("s_waitcnt vmcnt(4)" ::: "memory"); }
    else    { asm volatile("s_waitcnt vmcnt(0)" ::: "memory"); }
    BARX;
    // ---- P5: (qm0,qn01) of dbuf1 ----
    RD_A(0, 32768); RD_B2(0, 32768);
    if (nl) STG(Ab, 0, 0, 0, t2);
    BARX; PRIO1; MFMA_QUAD(0, 0); PRIO0; BARX;
    // ---- P6: (qm0,qn23) ----
    RD_B2(2, 32768);
    if (nl) STG(Ab, 0, 0, 1, t2);
    BARX; PRIO1; MFMA_QUAD(0, 2); PRIO0; BARX;
    // ---- P7: (qm1,qn23) ----
    RD_A(1, 32768);
    if (nl) STG(Bb, 1, 1, 0, t3);
    BARX; PRIO1; MFMA_QUAD(4, 2); PRIO0; BARX;
    // ---- P8: (qm1,qn01); dbuf0 must be complete after this phase ----
    if (nl) STG(Bb, 1, 1, 1, t3);
    BARX; PRIO1; MFMA_QUAD(4, 0); PRIO0;
    if (nl) { asm volatile("s_waitcnt vmcnt(4)" ::: "memory"); }
    BARX;
  }

  // epilogue
  const int cn = lane & 15;
  const int rr = (lane >> 4) * 4;
  const int row0 = by * 256 + wr * 128;
  const int col0 = bx * 256 + wc * 64;
#pragma unroll
  for (int m = 0; m < 8; ++m) {
    const int row = row0 + m * 16 + rr;
#pragma unroll
    for (int n = 0; n < 4; ++n) {
      const int col = col0 + n * 16 + cn;
      if (MODE == 0) {
        bf16_t* C = (bf16_t*)Cv;
        float bias = extra[col];
#pragma unroll
        for (int j = 0; j < 4; ++j)
          C[(long)(row + j) * N + col] = (bf16_t)(acc[m][n][j] + bias);
      } else if (MODE == 1) {
        bf16_t* C = (bf16_t*)Cv + (long)bz * sC;
        float mk = extra[(long)bz * sE + col];
#pragma unroll
        for (int j = 0; j < 4; ++j)
          C[(long)(row + j) * N + col] = (bf16_t)(acc[m][n][j] * 0.03125f + mk);
      } else {
        float* C = (float*)Cv + (long)bz * sC;
#pragma unroll
        for (int j = 0; j < 4; ++j)
          C[(long)(row + j) * N + col] = acc[m][n][j];
      }
    }
  }
}

// ---------------- row softmax, in-place on bf16 logits ----------------
__global__ __launch_bounds__(256) void softmax_rows(bf16_t* __restrict__ logits) {
  long row = blockIdx.x;
  bf16_t* p = logits + row * LK_;
  int t = threadIdx.x;
  int lane = t & 63, wave = t >> 6;
  bf16x8 v = *reinterpret_cast<const bf16x8*>(p + t * 8);
  float f[8];
  float mx = -3e38f;
#pragma unroll
  for (int j = 0; j < 8; ++j) {
    f[j] = (float)v[j];
    mx = fmaxf(mx, f[j]);
  }
#pragma unroll
  for (int off = 32; off > 0; off >>= 1) mx = fmaxf(mx, __shfl_xor(mx, off, 64));
  __shared__ float red[8];
  if (lane == 0) red[wave] = mx;
  __syncthreads();
  mx = fmaxf(fmaxf(red[0], red[1]), fmaxf(red[2], red[3]));
  float s = 0.f;
#pragma unroll
  for (int j = 0; j < 8; ++j) {
    f[j] = __expf(f[j] - mx);
    s += f[j];
  }
#pragma unroll
  for (int off = 32; off > 0; off >>= 1) s += __shfl_xor(s, off, 64);
  if (lane == 0) red[4 + wave] = s;
  __syncthreads();
  s = red[4] + red[5] + red[6] + red[7];
  float inv = 1.f / s;
#pragma unroll
  for (int j = 0; j < 8; ++j) v[j] = (bf16_t)(f[j] * inv);
  *reinterpret_cast<bf16x8*>(p + t * 8) = v;
}

extern "C" void kernel_launch(void* const* d_in, const int* in_sizes, int n_in,
                              void* d_out, int out_size, void* d_ws, size_t ws_size,
                              hipStream_t stream) {
  const float* x    = (const float*)d_in[0];
  const float* mask = (const float*)d_in[1];
  const float* keys = (const float*)d_in[2];
  const float* vals = (const float*)d_in[3];
  const float* Wq   = (const float*)d_in[4];
  const float* bq   = (const float*)d_in[5];
  float* out = (float*)d_out;

  char* ws = (char*)d_ws;
  bf16_t* kbf    = (bf16_t*)(ws);
  bf16_t* vt     = (bf16_t*)(ws + 33554432);
  bf16_t* qbf    = (bf16_t*)(ws + 67108864);
  bf16_t* logits = (bf16_t*)(ws + 100663296);
  bf16_t* xbf    = logits;  // reused: x_bf dead before logits are written
  bf16_t* wqbf   = (bf16_t*)(ws + 167772160);

  // 1. converts
  cvt_bf16_kernel<<<2048, 256, 0, stream>>>(x, xbf, (B_ * LQ_ * DM_) / 8);
  cvt_bf16_kernel<<<2048, 256, 0, stream>>>(keys, kbf, (B_ * LK_ * DM_) / 8);
  cvt_bf16_kernel<<<256, 256, 0, stream>>>(Wq, wqbf, (DM_ * DM_) / 8);
  transpose_v<<<dim3(LK_ / 64, DM_ / 64, B_), 256, 0, stream>>>(vals, vt);

  // 2. Q = x @ Wq^T + bq   (M=16384, N=1024, K=1024) grid 4x64 = 256
  gemm_bt<0><<<256, 512, 0, stream>>>(
      xbf, wqbf, qbf, bq, DM_, DM_, 0, 0, 0, 0, 2, 6);

  // 3. logits = Q @ K^T / 32 + mask (per batch M=2048,N=2048,K=1024) grid 8x8x8 = 512
  gemm_bt<1><<<512, 512, 0, stream>>>(
      qbf, kbf, logits, mask, LK_, DM_,
      (long)LQ_ * DM_, (long)LK_ * DM_, (long)LQ_ * LK_, LK_, 3, 3);

  // 4. softmax rows, in place
  softmax_rows<<<B_ * LQ_, 256, 0, stream>>>(logits);

  // 5. out = P @ Vt^T   (per batch M=2048, N=1024, K=2048) grid 4x8x8 = 256
  gemm_bt<2><<<256, 512, 0, stream>>>(
      logits, vt, out, nullptr, DM_, LK_,
      (long)LQ_ * LK_, (long)DM_ * LK_, (long)LQ_ * DM_, 0, 2, 3);
}